// Round 2
// 567.159 us; speedup vs baseline: 1.0227x; 1.0227x over previous
//
#include <hip/hip_runtime.h>

// DeepFilter, fused single kernel.
// out[b,0,t,f<256] = sum_k pr[t+k-4]*cr[k] - pi[t+k-4]*ci[k]
// out[b,1,t,f<256] = sum_k pi[t+k-4]*cr[k] + pr[t+k-4]*ci[k]
// out[..., f>=256] = spec[..., f>=256]
// spec  : (B, 2, T, 481) fp32
// coefs : (B, 10, T, 256) fp32 -> cr = coefs[b,k,t,f], ci = coefs[b,5+k,t,f]
//
// Design (R1, fixed compile):
//  - TT=4 t-tile per thread: 8-row spec window in registers, spec rows read
//    2x per output instead of 5x; VMEM insts/output 58 -> ~26.
//  - tail copy fused as grid-stride loop (replaces 65536-block df_tail).
//  - nontemporal on coefs loads (stream, no reuse) and all out stores.
//  - nontemporal builtins need a NATIVE clang vector type (ext_vector_type),
//    not HIP's float4 class -> use v4f below.

static constexpr int kB  = 8;
static constexpr int kT  = 4096;
static constexpr int kFT = 481;   // total freqs
static constexpr int kNF = 256;   // filtered freqs
static constexpr int kFS = 5;     // taps
static constexpr int kTT = 4;     // t-values per thread
static constexpr int kWin = kTT + kFS - 1;                 // 8 spec rows/thread
static constexpr int kTailF = kFT - kNF;                   // 225
static constexpr unsigned kTailElems = (unsigned)kB * 2u * kT * kTailF; // 14,745,600

typedef float v4f __attribute__((ext_vector_type(4)));

__global__ __launch_bounds__(256) void df_fused(const float* __restrict__ spec,
                                                const float* __restrict__ coefs,
                                                float* __restrict__ out) {
    // t-major: idx = tg*(B*64) + b*64 + f4 so concurrent blocks share spec
    // rows in L2 and tg, tg+1 (which re-read 4 of the same rows) are adjacent.
    const int idx = blockIdx.x * 256 + threadIdx.x;   // 524,288 threads total
    const int f4 = idx & 63;
    const int b  = (idx >> 6) & 7;
    const int tg = idx >> 9;                          // 0..1023
    const int t0 = tg * kTT;
    const int f  = f4 << 2;

    const float* sr = spec + (size_t)(b * 2    ) * kT * kFT + f;
    const float* si = spec + (size_t)(b * 2 + 1) * kT * kFT + f;

    // Spec window: slot r holds row tk = t0 - 4 + r, r = 0..7.
    // All indices compile-time after unroll -> stays in VGPRs (~64 regs).
    float prw[kWin][4];
    float piw[kWin][4];
#pragma unroll
    for (int r = 0; r < kWin; ++r) {
        const int tk = t0 - (kFS - 1) + r;
        if (tk >= 0) {   // only ever false for tg==0, r<4
            const float* pr = sr + (size_t)tk * kFT;
            const float* pi = si + (size_t)tk * kFT;
#pragma unroll
            for (int j = 0; j < 4; ++j) { prw[r][j] = pr[j]; piw[r][j] = pi[j]; }
        } else {
#pragma unroll
            for (int j = 0; j < 4; ++j) { prw[r][j] = 0.f; piw[r][j] = 0.f; }
        }
    }

#pragma unroll
    for (int tt = 0; tt < kTT; ++tt) {
        const int t = t0 + tt;
        float accR[4] = {0.f, 0.f, 0.f, 0.f};
        float accI[4] = {0.f, 0.f, 0.f, 0.f};
#pragma unroll
        for (int k = 0; k < kFS; ++k) {
            // coefs rows are 256-float stride -> 16B-aligned vector loads.
            // nontemporal: coefs are used exactly once, keep them out of L2's way.
            const v4f cr = __builtin_nontemporal_load(
                (const v4f*)(coefs + ((size_t)(b * 10 + k    ) * kT + t) * kNF + f));
            const v4f ci = __builtin_nontemporal_load(
                (const v4f*)(coefs + ((size_t)(b * 10 + 5 + k) * kT + t) * kNF + f));
            const int r = tt + k;   // window slot for tap k at time t0+tt
#pragma unroll
            for (int j = 0; j < 4; ++j) {
                accR[j] = fmaf(prw[r][j], cr[j], fmaf(-piw[r][j], ci[j], accR[j]));
                accI[j] = fmaf(piw[r][j], cr[j], fmaf( prw[r][j], ci[j], accI[j]));
            }
        }
        // out rows have odd stride 481 -> scalar stores (coalesced across wave).
        float* oR = out + ((size_t)(b * 2    ) * kT + t) * kFT + f;
        float* oI = out + ((size_t)(b * 2 + 1) * kT + t) * kFT + f;
#pragma unroll
        for (int j = 0; j < 4; ++j) {
            __builtin_nontemporal_store(accR[j], oR + j);
            __builtin_nontemporal_store(accI[j], oI + j);
        }
    }

    // ---- fused tail: out[..., 256:481] = spec[..., 256:481] ----
    // Grid-stride over 14.7M elements; consecutive lanes -> consecutive
    // addresses (coalesced except at 225-element row seams). /225 becomes
    // a magic multiply.
    const unsigned gsz = gridDim.x * 256u;
    for (unsigned i = (unsigned)idx; i < kTailElems; i += gsz) {
        const unsigned row = i / (unsigned)kTailF;
        const unsigned col = i - row * (unsigned)kTailF;
        const size_t off = (size_t)row * kFT + kNF + col;
        __builtin_nontemporal_store(__builtin_nontemporal_load(spec + off), out + off);
    }
}

extern "C" void kernel_launch(void* const* d_in, const int* in_sizes, int n_in,
                              void* d_out, int out_size, void* d_ws, size_t ws_size,
                              hipStream_t stream) {
    const float* spec  = (const float*)d_in[0];
    const float* coefs = (const float*)d_in[1];
    float* out = (float*)d_out;

    // B * (T/TT) * (NF/4) threads = 8 * 1024 * 64 = 524,288 -> 2048 blocks
    df_fused<<<(kB * (kT / kTT) * (kNF / 4)) / 256, 256, 0, stream>>>(spec, coefs, out);
}

// Round 3
// 565.466 us; speedup vs baseline: 1.0257x; 1.0030x over previous
//
#include <hip/hip_runtime.h>

// DeepFilter, fused single kernel. R3: dense-lane memory mapping.
// out[b,0,t,f<256] = sum_k pr[t+k-4]*cr[k] - pi[t+k-4]*ci[k]
// out[b,1,t,f<256] = sum_k pi[t+k-4]*cr[k] + pr[t+k-4]*ci[k]
// out[..., f>=256] = spec[..., f>=256]
// spec  : (B, 2, T, 481) fp32
// coefs : (B, 10, T, 256) fp32 -> cr = coefs[b,k,t,f], ci = coefs[b,5+k,t,f]
//
// R3 changes vs R2:
//  - Thread owns f = f4 + 64*j (strided-by-64) instead of 4 consecutive f.
//    Every wave64 scalar load/store is now LANE-CONSECUTIVE (dense 256 B
//    span, 4 fully-covered lines per inst). R2's consecutive-f mapping made
//    spec loads and df stores 16B-strided per inst (16 lines x 4 dwords),
//    relying on L2 merging that the `nt` hint may defeat (partial-line HBM
//    writeback = up to 4x write amplification on the df region).
//  - coefs: 4 scalar NT loads per (k,ch,t) instead of 1 dwordx4 — same
//    bytes, dense across wave; VMEM-issue floor is ~16 us, not binding.
//  - XCD-chunked block swizzle: all 2048 blocks co-resident; consecutive
//    tg's share 4 of 8 spec-window rows — keep them on the same XCD L2.

static constexpr int kB  = 8;
static constexpr int kT  = 4096;
static constexpr int kFT = 481;   // total freqs
static constexpr int kNF = 256;   // filtered freqs
static constexpr int kFS = 5;     // taps
static constexpr int kTT = 4;     // t-values per thread
static constexpr int kWin = kTT + kFS - 1;                 // 8 spec rows/thread
static constexpr int kTailF = kFT - kNF;                   // 225
static constexpr unsigned kTailElems = (unsigned)kB * 2u * kT * kTailF; // 14,745,600
static constexpr int kGrid = (kB * (kT / kTT) * (kNF / 4)) / 256;       // 2048 blocks

__global__ __launch_bounds__(256) void df_fused(const float* __restrict__ spec,
                                                const float* __restrict__ coefs,
                                                float* __restrict__ out) {
    // XCD-chunked swizzle: physical blocks round-robin XCDs by blockIdx%8.
    // Give XCD x the contiguous logical chunk [x*256, (x+1)*256) so the
    // overlapping spec windows of consecutive tg's hit the same XCD L2.
    const int lbid = (blockIdx.x & 7) * (kGrid / 8) + (blockIdx.x >> 3);
    const int idx  = lbid * 256 + (int)threadIdx.x;   // 524,288 threads
    const int f4 = idx & 63;
    const int b  = (idx >> 6) & 7;
    const int tg = idx >> 9;                          // 0..1023
    const int t0 = tg * kTT;

    // Dense-lane f mapping: this thread owns f_j = f4 + 64*j, j = 0..3.
    const float* sr = spec + (size_t)(b * 2) * kT * kFT + f4;
    const float* si = sr + (size_t)kT * kFT;

    // Spec window: slot r holds row tk = t0 - 4 + r, r = 0..7. (~64 VGPRs)
    float prw[kWin][4];
    float piw[kWin][4];
#pragma unroll
    for (int r = 0; r < kWin; ++r) {
        const int tk = t0 - (kFS - 1) + r;
        if (tk >= 0) {   // only false for tg==0, r<4
            const float* pr = sr + (size_t)tk * kFT;
            const float* pi = si + (size_t)tk * kFT;
#pragma unroll
            for (int j = 0; j < 4; ++j) { prw[r][j] = pr[64 * j]; piw[r][j] = pi[64 * j]; }
        } else {
#pragma unroll
            for (int j = 0; j < 4; ++j) { prw[r][j] = 0.f; piw[r][j] = 0.f; }
        }
    }

#pragma unroll
    for (int tt = 0; tt < kTT; ++tt) {
        const int t = t0 + tt;
        float accR[4] = {0.f, 0.f, 0.f, 0.f};
        float accI[4] = {0.f, 0.f, 0.f, 0.f};
#pragma unroll
        for (int k = 0; k < kFS; ++k) {
            // cr plane (b*10+k), ci plane (b*10+5+k); scalar NT loads,
            // lane-consecutive (dense 256 B per inst).
            const float* cb = coefs + ((size_t)(b * 10 + k) * kT + t) * kNF + f4;
            const int r = tt + k;   // window slot for tap k at time t0+tt
#pragma unroll
            for (int j = 0; j < 4; ++j) {
                const float cr = __builtin_nontemporal_load(cb + 64 * j);
                const float ci = __builtin_nontemporal_load(cb + (size_t)5 * kT * kNF + 64 * j);
                accR[j] = fmaf(prw[r][j], cr, fmaf(-piw[r][j], ci, accR[j]));
                accI[j] = fmaf(piw[r][j], cr, fmaf( prw[r][j], ci, accI[j]));
            }
        }
        // Dense scalar stores: inst j writes lanes 0..63 -> f = 0..63 + 64j,
        // a contiguous 256 B span of 4 fully-covered lines. NT is safe here.
        float* oR = out + ((size_t)(b * 2) * kT + t) * kFT + f4;
        float* oI = oR + (size_t)kT * kFT;
#pragma unroll
        for (int j = 0; j < 4; ++j) {
            __builtin_nontemporal_store(accR[j], oR + 64 * j);
            __builtin_nontemporal_store(accI[j], oI + 64 * j);
        }
    }

    // ---- fused tail: out[..., 256:481] = spec[..., 256:481] ----
    // Grid-stride over 14.7M elements; consecutive lanes -> consecutive
    // addresses (coalesced except at 225-element row seams). /225 is a
    // magic multiply. Mapping need not match the swizzle (bijective anyway).
    const int ridx = (int)blockIdx.x * 256 + (int)threadIdx.x;
    const unsigned gsz = (unsigned)kGrid * 256u;
    for (unsigned i = (unsigned)ridx; i < kTailElems; i += gsz) {
        const unsigned row = i / (unsigned)kTailF;
        const unsigned col = i - row * (unsigned)kTailF;
        const size_t off = (size_t)row * kFT + kNF + col;
        __builtin_nontemporal_store(__builtin_nontemporal_load(spec + off), out + off);
    }
}

extern "C" void kernel_launch(void* const* d_in, const int* in_sizes, int n_in,
                              void* d_out, int out_size, void* d_ws, size_t ws_size,
                              hipStream_t stream) {
    const float* spec  = (const float*)d_in[0];
    const float* coefs = (const float*)d_in[1];
    float* out = (float*)d_out;

    df_fused<<<kGrid, 256, 0, stream>>>(spec, coefs, out);
}

// Round 5
// 565.429 us; speedup vs baseline: 1.0258x; 1.0001x over previous
//
#include <hip/hip_runtime.h>

// DeepFilter, fused single kernel. R5 = R4 resubmitted (R4 bench was an
// infra failure, kernel never ran). Single-variable A/B: R3 minus all
// nontemporal hints.
// out[b,0,t,f<256] = sum_k pr[t+k-4]*cr[k] - pi[t+k-4]*ci[k]
// out[b,1,t,f<256] = sum_k pi[t+k-4]*cr[k] + pr[t+k-4]*ci[k]
// out[..., f>=256] = spec[..., f>=256]
// spec  : (B, 2, T, 481) fp32
// coefs : (B, 10, T, 256) fp32 -> cr = coefs[b,k,t,f], ci = coefs[b,5+k,t,f]
//
// Rationale: NT stores may defeat L2 write-combining on the 126 MB out
// stream (4B masked sectors to HBM); NT loads mark spec lines evict-first,
// breaking the 2x window-overlap reuse between adjacent tg's (+67 MB HBM).
// Everything else identical to R3 (dense-lane f mapping, XCD-chunked
// swizzle, fused grid-stride tail).

static constexpr int kB  = 8;
static constexpr int kT  = 4096;
static constexpr int kFT = 481;   // total freqs
static constexpr int kNF = 256;   // filtered freqs
static constexpr int kFS = 5;     // taps
static constexpr int kTT = 4;     // t-values per thread
static constexpr int kWin = kTT + kFS - 1;                 // 8 spec rows/thread
static constexpr int kTailF = kFT - kNF;                   // 225
static constexpr unsigned kTailElems = (unsigned)kB * 2u * kT * kTailF; // 14,745,600
static constexpr int kGrid = (kB * (kT / kTT) * (kNF / 4)) / 256;       // 2048 blocks

__global__ __launch_bounds__(256) void df_fused(const float* __restrict__ spec,
                                                const float* __restrict__ coefs,
                                                float* __restrict__ out) {
    // XCD-chunked swizzle: physical blocks round-robin XCDs by blockIdx%8;
    // give each XCD a contiguous logical tg-range so overlapping spec
    // windows stay in the same XCD L2.
    const int lbid = (blockIdx.x & 7) * (kGrid / 8) + (blockIdx.x >> 3);
    const int idx  = lbid * 256 + (int)threadIdx.x;   // 524,288 threads
    const int f4 = idx & 63;
    const int b  = (idx >> 6) & 7;
    const int tg = idx >> 9;                          // 0..1023
    const int t0 = tg * kTT;

    // Dense-lane f mapping: this thread owns f_j = f4 + 64*j, j = 0..3.
    const float* sr = spec + (size_t)(b * 2) * kT * kFT + f4;
    const float* si = sr + (size_t)kT * kFT;

    // Spec window: slot r holds row tk = t0 - 4 + r, r = 0..7. (~64 VGPRs)
    float prw[kWin][4];
    float piw[kWin][4];
#pragma unroll
    for (int r = 0; r < kWin; ++r) {
        const int tk = t0 - (kFS - 1) + r;
        if (tk >= 0) {   // only false for tg==0, r<4
            const float* pr = sr + (size_t)tk * kFT;
            const float* pi = si + (size_t)tk * kFT;
#pragma unroll
            for (int j = 0; j < 4; ++j) { prw[r][j] = pr[64 * j]; piw[r][j] = pi[64 * j]; }
        } else {
#pragma unroll
            for (int j = 0; j < 4; ++j) { prw[r][j] = 0.f; piw[r][j] = 0.f; }
        }
    }

#pragma unroll
    for (int tt = 0; tt < kTT; ++tt) {
        const int t = t0 + tt;
        float accR[4] = {0.f, 0.f, 0.f, 0.f};
        float accI[4] = {0.f, 0.f, 0.f, 0.f};
#pragma unroll
        for (int k = 0; k < kFS; ++k) {
            // cr plane (b*10+k), ci plane (b*10+5+k); plain scalar loads,
            // lane-consecutive (dense 256 B per inst).
            const float* cb = coefs + ((size_t)(b * 10 + k) * kT + t) * kNF + f4;
            const int r = tt + k;   // window slot for tap k at time t0+tt
#pragma unroll
            for (int j = 0; j < 4; ++j) {
                const float cr = cb[64 * j];
                const float ci = cb[(size_t)5 * kT * kNF + 64 * j];
                accR[j] = fmaf(prw[r][j], cr, fmaf(-piw[r][j], ci, accR[j]));
                accI[j] = fmaf(piw[r][j], cr, fmaf( prw[r][j], ci, accI[j]));
            }
        }
        // Dense scalar stores: inst j writes lanes 0..63 -> f = 0..63 + 64j,
        // a contiguous 256 B span of 4 fully-covered lines.
        float* oR = out + ((size_t)(b * 2) * kT + t) * kFT + f4;
        float* oI = oR + (size_t)kT * kFT;
#pragma unroll
        for (int j = 0; j < 4; ++j) {
            oR[64 * j] = accR[j];
            oI[64 * j] = accI[j];
        }
    }

    // ---- fused tail: out[..., 256:481] = spec[..., 256:481] ----
    // Grid-stride over 14.7M elements; consecutive lanes -> consecutive
    // addresses (coalesced except at 225-element row seams). /225 is a
    // magic multiply.
    const int ridx = (int)blockIdx.x * 256 + (int)threadIdx.x;
    const unsigned gsz = (unsigned)kGrid * 256u;
    for (unsigned i = (unsigned)ridx; i < kTailElems; i += gsz) {
        const unsigned row = i / (unsigned)kTailF;
        const unsigned col = i - row * (unsigned)kTailF;
        const size_t off = (size_t)row * kFT + kNF + col;
        out[off] = spec[off];
    }
}

extern "C" void kernel_launch(void* const* d_in, const int* in_sizes, int n_in,
                              void* d_out, int out_size, void* d_ws, size_t ws_size,
                              hipStream_t stream) {
    const float* spec  = (const float*)d_in[0];
    const float* coefs = (const float*)d_in[1];
    float* out = (float*)d_out;

    df_fused<<<kGrid, 256, 0, stream>>>(spec, coefs, out);
}